// Round 1
// baseline (1374.978 us; speedup 1.0000x reference)
//
#include <hip/hip_runtime.h>
#include <hip/hip_bf16.h>

// ---- problem constants ----
constexpr int BB  = 256;   // batch
constexpr int TT  = 1024;  // timesteps
constexpr int DXc = 64;
constexpr int DZc = 128;
constexpr int DBc = 16;
constexpr int TAUc = 25;
constexpr float CLIPV = 10.0f;
constexpr int NF = 40;     // forcing steps: t = 25..1000

// =====================================================================
// Fused 2-layer tanh MLP:  out = tanh(tanh(in@w1^T + b1)@w2^T + b2)
// Used for encoder (gathered 40 forcing timesteps) and decoder (all t).
// Block: 256 threads, ROWS rows per block. Weights staged transposed
// (XOR-swizzled to tame staging write bank conflicts). Compute reads are
// broadcast/4-way at worst.
// =====================================================================
template<int DIN, int DHID, int DOUT, int ROWS, bool GATHER, bool ALIAS>
__global__ __launch_bounds__(256, 1) void mlp_kernel(
    const float* __restrict__ in, const float* __restrict__ w1,
    const float* __restrict__ b1v, const float* __restrict__ w2,
    const float* __restrict__ b2v, float* __restrict__ out)
{
  static_assert(!ALIAS || DIN == DHID, "alias requires DIN==DHID");
  static_assert(DHID == 128, "layer1 tiling assumes DHID==128");
  constexpr int RT = ROWS / 16;   // rows per thread
  constexpr int OT = DOUT / 16;   // layer-2 outputs per thread

  __shared__ float w1t[DIN * DHID];            // [i][o^sw]
  __shared__ float w2t[DHID * DOUT];           // [j][o^sw]
  __shared__ float xs[ROWS * DIN];             // [r][i]
  __shared__ float ht_sep[ALIAS ? 4 : ROWS * DHID];
  float* htp = ALIAS ? xs : ht_sep;

  const int tid = threadIdx.x;
  const int to = tid & 15, tr = tid >> 4;
  const int row0 = blockIdx.x * ROWS;

  // ---- stage weights (transposed + swizzled) ----
  for (int idx = tid; idx < DHID * DIN; idx += 256) {
    const int o = idx / DIN, i = idx - o * DIN;
    w1t[i * DHID + (o ^ ((i & 7) << 2))] = w1[idx];
  }
  for (int idx = tid; idx < DOUT * DHID; idx += 256) {
    const int o = idx / DHID, j = idx - o * DHID;
    w2t[j * DOUT + (o ^ ((j & 7) << 2))] = w2[idx];
  }
  // ---- stage input rows ----
  for (int idx = tid; idx < ROWS * DIN; idx += 256) {
    const int r = idx / DIN, i = idx - r * DIN;
    const int rg = row0 + r;
    size_t off;
    if constexpr (GATHER) {
      const int f = rg >> 8, b = rg & 255;
      const int t = TAUc * (f + 1);
      off = ((size_t)b * TT + t) * (size_t)DIN;
    } else {
      off = (size_t)rg * DIN;
    }
    xs[idx] = in[off + i];
  }
  __syncthreads();

  // ---- layer 1: acc[RT][8] over DIN ----
  float acc[RT][8];
  #pragma unroll
  for (int a = 0; a < RT; ++a)
    #pragma unroll
    for (int c = 0; c < 8; ++c) acc[a][c] = 0.f;

  for (int i = 0; i < DIN; i += 4) {
    float4 xv[RT];
    #pragma unroll
    for (int a = 0; a < RT; ++a)
      xv[a] = *(const float4*)&xs[(tr * RT + a) * DIN + i];
    #pragma unroll
    for (int ii = 0; ii < 4; ++ii) {
      const int irow = i + ii;
      const int sw = (irow & 7) << 2;
      const float4 wv0 = *(const float4*)&w1t[irow * DHID + ((to * 8 + 0) ^ sw)];
      const float4 wv1 = *(const float4*)&w1t[irow * DHID + ((to * 8 + 4) ^ sw)];
      #pragma unroll
      for (int a = 0; a < RT; ++a) {
        const float xa = reinterpret_cast<const float*>(&xv[a])[ii];
        acc[a][0] = fmaf(xa, wv0.x, acc[a][0]);
        acc[a][1] = fmaf(xa, wv0.y, acc[a][1]);
        acc[a][2] = fmaf(xa, wv0.z, acc[a][2]);
        acc[a][3] = fmaf(xa, wv0.w, acc[a][3]);
        acc[a][4] = fmaf(xa, wv1.x, acc[a][4]);
        acc[a][5] = fmaf(xa, wv1.y, acc[a][5]);
        acc[a][6] = fmaf(xa, wv1.z, acc[a][6]);
        acc[a][7] = fmaf(xa, wv1.w, acc[a][7]);
      }
    }
  }

  __syncthreads();   // all xs reads done (needed when ALIAS)
  #pragma unroll
  for (int a = 0; a < RT; ++a) {
    #pragma unroll
    for (int c4 = 0; c4 < 2; ++c4) {
      float4 hv;
      hv.x = tanhf(acc[a][c4 * 4 + 0] + b1v[to * 8 + c4 * 4 + 0]);
      hv.y = tanhf(acc[a][c4 * 4 + 1] + b1v[to * 8 + c4 * 4 + 1]);
      hv.z = tanhf(acc[a][c4 * 4 + 2] + b1v[to * 8 + c4 * 4 + 2]);
      hv.w = tanhf(acc[a][c4 * 4 + 3] + b1v[to * 8 + c4 * 4 + 3]);
      *(float4*)&htp[(tr * RT + a) * DHID + to * 8 + c4 * 4] = hv;
    }
  }
  __syncthreads();

  // ---- layer 2: acc2[RT][OT] over DHID ----
  float acc2[RT][OT];
  #pragma unroll
  for (int a = 0; a < RT; ++a)
    #pragma unroll
    for (int c = 0; c < OT; ++c) acc2[a][c] = 0.f;

  for (int j = 0; j < DHID; j += 4) {
    float4 hv[RT];
    #pragma unroll
    for (int a = 0; a < RT; ++a)
      hv[a] = *(const float4*)&htp[(tr * RT + a) * DHID + j];
    #pragma unroll
    for (int jj = 0; jj < 4; ++jj) {
      const int jrow = j + jj;
      const int sw = (jrow & 7) << 2;
      #pragma unroll
      for (int c4 = 0; c4 < OT / 4; ++c4) {
        const float4 wv = *(const float4*)&w2t[jrow * DOUT + ((to * OT + c4 * 4) ^ sw)];
        #pragma unroll
        for (int a = 0; a < RT; ++a) {
          const float ha = reinterpret_cast<const float*>(&hv[a])[jj];
          acc2[a][c4 * 4 + 0] = fmaf(ha, wv.x, acc2[a][c4 * 4 + 0]);
          acc2[a][c4 * 4 + 1] = fmaf(ha, wv.y, acc2[a][c4 * 4 + 1]);
          acc2[a][c4 * 4 + 2] = fmaf(ha, wv.z, acc2[a][c4 * 4 + 2]);
          acc2[a][c4 * 4 + 3] = fmaf(ha, wv.w, acc2[a][c4 * 4 + 3]);
        }
      }
    }
  }

  // ---- bias + tanh + store ----
  #pragma unroll
  for (int a = 0; a < RT; ++a) {
    const int rg = row0 + tr * RT + a;
    size_t ooff;
    if constexpr (GATHER) {
      const int f = rg >> 8, b = rg & 255;
      const int t = TAUc * (f + 1);
      ooff = ((size_t)b * TT + t) * (size_t)DOUT;
    } else {
      ooff = (size_t)rg * DOUT;
    }
    #pragma unroll
    for (int c4 = 0; c4 < OT / 4; ++c4) {
      float4 ov;
      ov.x = tanhf(acc2[a][c4 * 4 + 0] + b2v[to * OT + c4 * 4 + 0]);
      ov.y = tanhf(acc2[a][c4 * 4 + 1] + b2v[to * OT + c4 * 4 + 1]);
      ov.z = tanhf(acc2[a][c4 * 4 + 2] + b2v[to * OT + c4 * 4 + 2]);
      ov.w = tanhf(acc2[a][c4 * 4 + 3] + b2v[to * OT + c4 * 4 + 3]);
      *(float4*)&out[ooff + to * OT + c4 * 4] = ov;
    }
  }
}

// =====================================================================
// Scan kernel: one block per batch row, 2 waves (128 threads).
// Lane L of wave w: replicated z-state pair (z[L], z[L+64]); owns output
// k = w*64+L with its W row in registers (64 float2). One raw s_barrier
// per step (state exchange, double-buffered); no vmcnt drain, so the
// per-step z_seq store stays fire-and-forget.
// =====================================================================
__global__ __launch_bounds__(128, 1) void scan_kernel(
    const float* __restrict__ AW, const float* __restrict__ z0,
    const float* __restrict__ hvec, const float* __restrict__ alphas,
    const float* __restrict__ thetas, float* __restrict__ zs)
{
  const int b = blockIdx.x;
  const int tid = threadIdx.x;
  const int w = tid >> 6;       // wave 0/1
  const int L = tid & 63;
  const int kown = tid;         // = w*64 + L
  const int klo = L, khi = L + 64;

  __shared__ float basis_lds[2][DZc];  // per-wave private copy
  __shared__ float zx[2][DZc];         // state exchange, double-buffered

  // W row of kown in registers (pairs over j), diag removed
  float2 wpk[64];
  #pragma unroll
  for (int jj = 0; jj < 64; ++jj) {
    const int j0 = 2 * jj, j1 = 2 * jj + 1;
    wpk[jj].x = (j0 == kown) ? 0.f : AW[kown * DZc + j0];
    wpk[jj].y = (j1 == kown) ? 0.f : AW[kown * DZc + j1];
  }
  const float a_k = AW[kown * DZc + kown];
  const float h_k = hvec[kown];
  float al[DBc];
  #pragma unroll
  for (int d = 0; d < DBc; ++d) al[d] = alphas[d];
  float2 th[DBc];
  #pragma unroll
  for (int d = 0; d < DBc; ++d) {
    th[d].x = thetas[klo * DBc + d];
    th[d].y = thetas[khi * DBc + d];
  }

  float zlo = z0[b * DZc + klo];
  float zhi = z0[b * DZc + khi];

  int next_tf = TAUc;
  // prefetch encoder stash (written by enc kernel into zs forcing slots)
  float fz = zs[(size_t)b * TT * DZc + (size_t)TAUc * DZc + kown];

  const size_t zbase = (size_t)b * TT * DZc;

  for (int t = 0; t < TT; ++t) {
    // mean over all 128 components (in-wave butterfly on pair sums)
    float s = zlo + zhi;
    #pragma unroll
    for (int m = 1; m < 64; m <<= 1) s += __shfl_xor(s, m, 64);
    const float mean = s * (1.0f / 128.0f);

    // basis for the pair
    const float zclo = zlo - mean, zchi = zhi - mean;
    float blo = 0.f, bhi = 0.f;
    #pragma unroll
    for (int d = 0; d < DBc; ++d) {
      blo = fmaf(al[d], fmaxf(zclo + th[d].x, 0.f), blo);
      bhi = fmaf(al[d], fmaxf(zchi + th[d].y, 0.f), bhi);
    }
    basis_lds[w][klo] = blo;
    basis_lds[w][khi] = bhi;
    // (own-wave RAW: compiler inserts lgkmcnt wait)

    // matvec: z_next[kown] partials over all 128 j (even/odd accumulators)
    float ae = 0.f, ao = 0.f;
    #pragma unroll
    for (int q = 0; q < 32; ++q) {
      const float4 bb = *(const float4*)&basis_lds[w][q * 4];
      ae = fmaf(bb.x, wpk[2 * q].x, ae);
      ao = fmaf(bb.y, wpk[2 * q].y, ao);
      ae = fmaf(bb.z, wpk[2 * q + 1].x, ae);
      ao = fmaf(bb.w, wpk[2 * q + 1].y, ao);
    }
    const float zown = w ? zhi : zlo;
    float zn = fmaf(a_k, zown, h_k) + (ae + ao);
    zn = fminf(fmaxf(zn, -CLIPV), CLIPV);

    zs[zbase + (size_t)t * DZc + kown] = zn;   // fire-and-forget store

    // next state (apply teacher forcing for step t+1 now)
    float state = zn;
    if (t + 1 == next_tf) {
      state = fz;
      next_tf += TAUc;
      if (next_tf <= 1000)
        fz = zs[zbase + (size_t)next_tf * DZc + kown];
    }

    // exchange halves (double-buffered, single raw barrier: lgkm only,
    // no vmcnt drain)
    zx[t & 1][kown] = state;
    __asm__ volatile("s_waitcnt lgkmcnt(0)" ::: "memory");
    __builtin_amdgcn_s_barrier();
    __asm__ volatile("" ::: "memory");
    const float zoth = zx[t & 1][w ? klo : khi];
    zlo = w ? zoth : state;
    zhi = w ? state : zoth;
  }
}

extern "C" void kernel_launch(void* const* d_in, const int* in_sizes, int n_in,
                              void* d_out, int out_size, void* d_ws, size_t ws_size,
                              hipStream_t stream) {
  const float* x      = (const float*)d_in[0];
  const float* z0     = (const float*)d_in[1];
  const float* AW     = (const float*)d_in[2];
  const float* hvec   = (const float*)d_in[3];
  const float* alphas = (const float*)d_in[4];
  const float* thetas = (const float*)d_in[5];
  const float* ew1    = (const float*)d_in[6];
  const float* eb1    = (const float*)d_in[7];
  const float* ew2    = (const float*)d_in[8];
  const float* eb2    = (const float*)d_in[9];
  const float* dw1    = (const float*)d_in[10];
  const float* db1    = (const float*)d_in[11];
  const float* dw2    = (const float*)d_in[12];
  const float* db2    = (const float*)d_in[13];

  float* xp = (float*)d_out;                       // (B,T,DX)
  float* zs = xp + (size_t)BB * TT * DXc;          // (B,T,DZ)

  // 1) encoder at the 40 forcing timesteps -> stash into zs slots
  //    (scan reads each stash slot before overwriting it)
  hipLaunchKernelGGL((mlp_kernel<DXc, DZc, DZc, 32, true, false>),
                     dim3(NF * BB / 32), dim3(256), 0, stream,
                     x, ew1, eb1, ew2, eb2, zs);

  // 2) recurrence scan: one block per batch row
  hipLaunchKernelGGL(scan_kernel, dim3(BB), dim3(128), 0, stream,
                     AW, z0, hvec, alphas, thetas, zs);

  // 3) decoder over all (b,t)
  hipLaunchKernelGGL((mlp_kernel<DZc, DZc, DXc, 64, false, true>),
                     dim3(BB * TT / 64), dim3(256), 0, stream,
                     zs, dw1, db1, dw2, db2, xp);
}

// Round 2
// 1249.977 us; speedup vs baseline: 1.1000x; 1.1000x over previous
//
#include <hip/hip_runtime.h>
#include <hip/hip_bf16.h>

// ---- problem constants ----
constexpr int BB  = 256;   // batch
constexpr int TT  = 1024;  // timesteps
constexpr int DXc = 64;
constexpr int DZc = 128;
constexpr int DBc = 16;
constexpr int TAUc = 25;
constexpr float CLIPV = 10.0f;
constexpr int NF = 40;     // forcing steps: t = 25..1000

// =====================================================================
// Fused 2-layer tanh MLP:  out = tanh(tanh(in@w1^T + b1)@w2^T + b2)
// (unchanged this round; scan is the bottleneck)
// =====================================================================
template<int DIN, int DHID, int DOUT, int ROWS, bool GATHER, bool ALIAS>
__global__ __launch_bounds__(256, 1) void mlp_kernel(
    const float* __restrict__ in, const float* __restrict__ w1,
    const float* __restrict__ b1v, const float* __restrict__ w2,
    const float* __restrict__ b2v, float* __restrict__ out)
{
  static_assert(!ALIAS || DIN == DHID, "alias requires DIN==DHID");
  static_assert(DHID == 128, "layer1 tiling assumes DHID==128");
  constexpr int RT = ROWS / 16;   // rows per thread
  constexpr int OT = DOUT / 16;   // layer-2 outputs per thread

  __shared__ float w1t[DIN * DHID];            // [i][o^sw]
  __shared__ float w2t[DHID * DOUT];           // [j][o^sw]
  __shared__ float xs[ROWS * DIN];             // [r][i]
  __shared__ float ht_sep[ALIAS ? 4 : ROWS * DHID];
  float* htp = ALIAS ? xs : ht_sep;

  const int tid = threadIdx.x;
  const int to = tid & 15, tr = tid >> 4;
  const int row0 = blockIdx.x * ROWS;

  for (int idx = tid; idx < DHID * DIN; idx += 256) {
    const int o = idx / DIN, i = idx - o * DIN;
    w1t[i * DHID + (o ^ ((i & 7) << 2))] = w1[idx];
  }
  for (int idx = tid; idx < DOUT * DHID; idx += 256) {
    const int o = idx / DHID, j = idx - o * DHID;
    w2t[j * DOUT + (o ^ ((j & 7) << 2))] = w2[idx];
  }
  for (int idx = tid; idx < ROWS * DIN; idx += 256) {
    const int r = idx / DIN, i = idx - r * DIN;
    const int rg = row0 + r;
    size_t off;
    if constexpr (GATHER) {
      const int f = rg >> 8, b = rg & 255;
      const int t = TAUc * (f + 1);
      off = ((size_t)b * TT + t) * (size_t)DIN;
    } else {
      off = (size_t)rg * DIN;
    }
    xs[idx] = in[off + i];
  }
  __syncthreads();

  float acc[RT][8];
  #pragma unroll
  for (int a = 0; a < RT; ++a)
    #pragma unroll
    for (int c = 0; c < 8; ++c) acc[a][c] = 0.f;

  for (int i = 0; i < DIN; i += 4) {
    float4 xv[RT];
    #pragma unroll
    for (int a = 0; a < RT; ++a)
      xv[a] = *(const float4*)&xs[(tr * RT + a) * DIN + i];
    #pragma unroll
    for (int ii = 0; ii < 4; ++ii) {
      const int irow = i + ii;
      const int sw = (irow & 7) << 2;
      const float4 wv0 = *(const float4*)&w1t[irow * DHID + ((to * 8 + 0) ^ sw)];
      const float4 wv1 = *(const float4*)&w1t[irow * DHID + ((to * 8 + 4) ^ sw)];
      #pragma unroll
      for (int a = 0; a < RT; ++a) {
        const float xa = reinterpret_cast<const float*>(&xv[a])[ii];
        acc[a][0] = fmaf(xa, wv0.x, acc[a][0]);
        acc[a][1] = fmaf(xa, wv0.y, acc[a][1]);
        acc[a][2] = fmaf(xa, wv0.z, acc[a][2]);
        acc[a][3] = fmaf(xa, wv0.w, acc[a][3]);
        acc[a][4] = fmaf(xa, wv1.x, acc[a][4]);
        acc[a][5] = fmaf(xa, wv1.y, acc[a][5]);
        acc[a][6] = fmaf(xa, wv1.z, acc[a][6]);
        acc[a][7] = fmaf(xa, wv1.w, acc[a][7]);
      }
    }
  }

  __syncthreads();   // all xs reads done (needed when ALIAS)
  #pragma unroll
  for (int a = 0; a < RT; ++a) {
    #pragma unroll
    for (int c4 = 0; c4 < 2; ++c4) {
      float4 hv;
      hv.x = tanhf(acc[a][c4 * 4 + 0] + b1v[to * 8 + c4 * 4 + 0]);
      hv.y = tanhf(acc[a][c4 * 4 + 1] + b1v[to * 8 + c4 * 4 + 1]);
      hv.z = tanhf(acc[a][c4 * 4 + 2] + b1v[to * 8 + c4 * 4 + 2]);
      hv.w = tanhf(acc[a][c4 * 4 + 3] + b1v[to * 8 + c4 * 4 + 3]);
      *(float4*)&htp[(tr * RT + a) * DHID + to * 8 + c4 * 4] = hv;
    }
  }
  __syncthreads();

  float acc2[RT][OT];
  #pragma unroll
  for (int a = 0; a < RT; ++a)
    #pragma unroll
    for (int c = 0; c < OT; ++c) acc2[a][c] = 0.f;

  for (int j = 0; j < DHID; j += 4) {
    float4 hv[RT];
    #pragma unroll
    for (int a = 0; a < RT; ++a)
      hv[a] = *(const float4*)&htp[(tr * RT + a) * DHID + j];
    #pragma unroll
    for (int jj = 0; jj < 4; ++jj) {
      const int jrow = j + jj;
      const int sw = (jrow & 7) << 2;
      #pragma unroll
      for (int c4 = 0; c4 < OT / 4; ++c4) {
        const float4 wv = *(const float4*)&w2t[jrow * DOUT + ((to * OT + c4 * 4) ^ sw)];
        #pragma unroll
        for (int a = 0; a < RT; ++a) {
          const float ha = reinterpret_cast<const float*>(&hv[a])[jj];
          acc2[a][c4 * 4 + 0] = fmaf(ha, wv.x, acc2[a][c4 * 4 + 0]);
          acc2[a][c4 * 4 + 1] = fmaf(ha, wv.y, acc2[a][c4 * 4 + 1]);
          acc2[a][c4 * 4 + 2] = fmaf(ha, wv.z, acc2[a][c4 * 4 + 2]);
          acc2[a][c4 * 4 + 3] = fmaf(ha, wv.w, acc2[a][c4 * 4 + 3]);
        }
      }
    }
  }

  #pragma unroll
  for (int a = 0; a < RT; ++a) {
    const int rg = row0 + tr * RT + a;
    size_t ooff;
    if constexpr (GATHER) {
      const int f = rg >> 8, b = rg & 255;
      const int t = TAUc * (f + 1);
      ooff = ((size_t)b * TT + t) * (size_t)DOUT;
    } else {
      ooff = (size_t)rg * DOUT;
    }
    #pragma unroll
    for (int c4 = 0; c4 < OT / 4; ++c4) {
      float4 ov;
      ov.x = tanhf(acc2[a][c4 * 4 + 0] + b2v[to * OT + c4 * 4 + 0]);
      ov.y = tanhf(acc2[a][c4 * 4 + 1] + b2v[to * OT + c4 * 4 + 1]);
      ov.z = tanhf(acc2[a][c4 * 4 + 2] + b2v[to * OT + c4 * 4 + 2]);
      ov.w = tanhf(acc2[a][c4 * 4 + 3] + b2v[to * OT + c4 * 4 + 3]);
      *(float4*)&out[ooff + to * OT + c4 * 4] = ov;
    }
  }
}

// =====================================================================
// Scan kernel v2: one block per batch row, 4 waves (256 threads).
// Wave roles (L = lane, jh = w&1 = matvec j-half):
//   w0: output k=L,    jh=0      w1: output k=64+L, jh=1
//   w2: output k=64+L, jh=0      w3: output k=L,    jh=1
// Each lane: 64 W floats in VGPRs (half a row -> no spill), replicated
// state pair (zA=z[L], zB=z[64+L]) so the mean is a pure in-wave
// butterfly and BOTH next-state components are recomputed redundantly
// by every lane -> only ONE raw s_barrier per step (partial combine),
// lgkm-only (global stores stay fire-and-forget).
// =====================================================================
__global__ __launch_bounds__(256, 1) void scan_kernel(
    const float* __restrict__ AW, const float* __restrict__ z0,
    const float* __restrict__ hvec, const float* __restrict__ alphas,
    const float* __restrict__ thetas, float* __restrict__ zs)
{
  const int b = blockIdx.x;
  const int tid = threadIdx.x;
  const int w = tid >> 6;
  const int L = tid & 63;
  const int jh = w & 1;                              // j-half for matvec
  const int k = ((w == 1) || (w == 2)) ? (64 + L) : L; // owned output
  const int c = jh * 64 + L;                         // basis component computed

  __shared__ float basis_w[4][64];   // per-wave private basis copy
  __shared__ float pl[2][2][128];    // [buf][jhalf][k] partial sums

  // --- W half-row in registers (diag removed) ---
  float Wreg[64];
  #pragma unroll 64
  for (int j = 0; j < 64; ++j) {
    const int jj = jh * 64 + j;
    Wreg[j] = (jj == k) ? 0.f : AW[k * DZc + jj];
  }
  const float aA = AW[L * DZc + L];
  const float aB = AW[(64 + L) * DZc + (64 + L)];
  const float hA = hvec[L];
  const float hB = hvec[64 + L];

  float al[DBc], th[DBc];
  #pragma unroll
  for (int d = 0; d < DBc; ++d) {
    al[d] = alphas[d];
    th[d] = thetas[c * DBc + d];
  }

  float zA = z0[b * DZc + L];
  float zB = z0[b * DZc + 64 + L];

  const size_t zbase = (size_t)b * TT * DZc;
  int next_tf = TAUc;
  float fzA = zs[zbase + (size_t)TAUc * DZc + L];
  float fzB = zs[zbase + (size_t)TAUc * DZc + 64 + L];

  for (int t = 0; t < TT; ++t) {
    // mean over 128 components: in-wave butterfly on pair sums
    float s = zA + zB;
    #pragma unroll
    for (int m = 1; m < 64; m <<= 1) s += __shfl_xor(s, m, 64);
    const float mean = s * (1.0f / 128.0f);

    // basis for this lane's component c
    const float zc = (jh ? zB : zA) - mean;
    float bsum = 0.f;
    #pragma unroll
    for (int d = 0; d < DBc; ++d)
      bsum = fmaf(al[d], fmaxf(zc + th[d], 0.f), bsum);
    basis_w[w][L] = bsum;     // wave-private; in-order DS RAW, lgkm only

    // half-row matvec, 4 independent accumulators
    float p0 = 0.f, p1 = 0.f, p2 = 0.f, p3 = 0.f;
    #pragma unroll
    for (int q = 0; q < 16; ++q) {
      const float4 bb = *(const float4*)&basis_w[w][q * 4];
      p0 = fmaf(bb.x, Wreg[q * 4 + 0], p0);
      p1 = fmaf(bb.y, Wreg[q * 4 + 1], p1);
      p2 = fmaf(bb.z, Wreg[q * 4 + 2], p2);
      p3 = fmaf(bb.w, Wreg[q * 4 + 3], p3);
    }
    const float p = (p0 + p1) + (p2 + p3);

    // publish partial, single lgkm-only barrier
    pl[t & 1][jh][k] = p;
    __asm__ volatile("s_waitcnt lgkmcnt(0)" ::: "memory");
    __builtin_amdgcn_s_barrier();
    __asm__ volatile("" ::: "memory");

    // every lane redundantly finishes BOTH components -> no 2nd barrier
    const float pA = pl[t & 1][0][L]      + pl[t & 1][1][L];
    const float pB = pl[t & 1][0][64 + L] + pl[t & 1][1][64 + L];
    float znA = fmaf(aA, zA, hA) + pA;
    float znB = fmaf(aB, zB, hB) + pB;
    znA = fminf(fmaxf(znA, -CLIPV), CLIPV);
    znB = fminf(fmaxf(znB, -CLIPV), CLIPV);

    // fire-and-forget store (waves 0/1 only)
    if (w == 0)      zs[zbase + (size_t)t * DZc + L]      = znA;
    else if (w == 1) zs[zbase + (size_t)t * DZc + 64 + L] = znB;

    zA = znA; zB = znB;
    if (t + 1 == next_tf) {            // teacher forcing for step t+1
      zA = fzA; zB = fzB;
      next_tf += TAUc;
      if (next_tf <= 1000) {           // prefetch next stash (slot still intact)
        fzA = zs[zbase + (size_t)next_tf * DZc + L];
        fzB = zs[zbase + (size_t)next_tf * DZc + 64 + L];
      }
    }
  }
}

extern "C" void kernel_launch(void* const* d_in, const int* in_sizes, int n_in,
                              void* d_out, int out_size, void* d_ws, size_t ws_size,
                              hipStream_t stream) {
  const float* x      = (const float*)d_in[0];
  const float* z0     = (const float*)d_in[1];
  const float* AW     = (const float*)d_in[2];
  const float* hvec   = (const float*)d_in[3];
  const float* alphas = (const float*)d_in[4];
  const float* thetas = (const float*)d_in[5];
  const float* ew1    = (const float*)d_in[6];
  const float* eb1    = (const float*)d_in[7];
  const float* ew2    = (const float*)d_in[8];
  const float* eb2    = (const float*)d_in[9];
  const float* dw1    = (const float*)d_in[10];
  const float* db1    = (const float*)d_in[11];
  const float* dw2    = (const float*)d_in[12];
  const float* db2    = (const float*)d_in[13];

  float* xp = (float*)d_out;                       // (B,T,DX)
  float* zs = xp + (size_t)BB * TT * DXc;          // (B,T,DZ)

  // 1) encoder at the 40 forcing timesteps -> stash into zs slots
  hipLaunchKernelGGL((mlp_kernel<DXc, DZc, DZc, 32, true, false>),
                     dim3(NF * BB / 32), dim3(256), 0, stream,
                     x, ew1, eb1, ew2, eb2, zs);

  // 2) recurrence scan: one block per batch row, 4 waves
  hipLaunchKernelGGL(scan_kernel, dim3(BB), dim3(256), 0, stream,
                     AW, z0, hvec, alphas, thetas, zs);

  // 3) decoder over all (b,t)
  hipLaunchKernelGGL((mlp_kernel<DZc, DZc, DXc, 64, false, true>),
                     dim3(BB * TT / 64), dim3(256), 0, stream,
                     zs, dw1, db1, dw2, db2, xp);
}

// Round 3
// 752.031 us; speedup vs baseline: 1.8284x; 1.6621x over previous
//
#include <hip/hip_runtime.h>
#include <hip/hip_bf16.h>

// ---- problem constants ----
constexpr int BB  = 256;   // batch
constexpr int TT  = 1024;  // timesteps
constexpr int DXc = 64;
constexpr int DZc = 128;
constexpr int DBc = 16;
constexpr int TAUc = 25;
constexpr float CLIPV = 10.0f;
constexpr int NF = 40;     // forcing steps: t = 25..1000
constexpr int NSEG = 41;   // independent scan segments (forcing breaks chain)

// =====================================================================
// Fused 2-layer tanh MLP:  out = tanh(tanh(in@w1^T + b1)@w2^T + b2)
// (unchanged this round; scan is still the bottleneck)
// =====================================================================
template<int DIN, int DHID, int DOUT, int ROWS, bool GATHER, bool ALIAS>
__global__ __launch_bounds__(256, 1) void mlp_kernel(
    const float* __restrict__ in, const float* __restrict__ w1,
    const float* __restrict__ b1v, const float* __restrict__ w2,
    const float* __restrict__ b2v, float* __restrict__ out)
{
  static_assert(!ALIAS || DIN == DHID, "alias requires DIN==DHID");
  static_assert(DHID == 128, "layer1 tiling assumes DHID==128");
  constexpr int RT = ROWS / 16;   // rows per thread
  constexpr int OT = DOUT / 16;   // layer-2 outputs per thread

  __shared__ float w1t[DIN * DHID];            // [i][o^sw]
  __shared__ float w2t[DHID * DOUT];           // [j][o^sw]
  __shared__ float xs[ROWS * DIN];             // [r][i]
  __shared__ float ht_sep[ALIAS ? 4 : ROWS * DHID];
  float* htp = ALIAS ? xs : ht_sep;

  const int tid = threadIdx.x;
  const int to = tid & 15, tr = tid >> 4;
  const int row0 = blockIdx.x * ROWS;

  for (int idx = tid; idx < DHID * DIN; idx += 256) {
    const int o = idx / DIN, i = idx - o * DIN;
    w1t[i * DHID + (o ^ ((i & 7) << 2))] = w1[idx];
  }
  for (int idx = tid; idx < DOUT * DHID; idx += 256) {
    const int o = idx / DHID, j = idx - o * DHID;
    w2t[j * DOUT + (o ^ ((j & 7) << 2))] = w2[idx];
  }
  for (int idx = tid; idx < ROWS * DIN; idx += 256) {
    const int r = idx / DIN, i = idx - r * DIN;
    const int rg = row0 + r;
    size_t off;
    if constexpr (GATHER) {
      const int f = rg >> 8, b = rg & 255;
      const int t = TAUc * (f + 1);
      off = ((size_t)b * TT + t) * (size_t)DIN;
    } else {
      off = (size_t)rg * DIN;
    }
    xs[idx] = in[off + i];
  }
  __syncthreads();

  float acc[RT][8];
  #pragma unroll
  for (int a = 0; a < RT; ++a)
    #pragma unroll
    for (int c = 0; c < 8; ++c) acc[a][c] = 0.f;

  for (int i = 0; i < DIN; i += 4) {
    float4 xv[RT];
    #pragma unroll
    for (int a = 0; a < RT; ++a)
      xv[a] = *(const float4*)&xs[(tr * RT + a) * DIN + i];
    #pragma unroll
    for (int ii = 0; ii < 4; ++ii) {
      const int irow = i + ii;
      const int sw = (irow & 7) << 2;
      const float4 wv0 = *(const float4*)&w1t[irow * DHID + ((to * 8 + 0) ^ sw)];
      const float4 wv1 = *(const float4*)&w1t[irow * DHID + ((to * 8 + 4) ^ sw)];
      #pragma unroll
      for (int a = 0; a < RT; ++a) {
        const float xa = reinterpret_cast<const float*>(&xv[a])[ii];
        acc[a][0] = fmaf(xa, wv0.x, acc[a][0]);
        acc[a][1] = fmaf(xa, wv0.y, acc[a][1]);
        acc[a][2] = fmaf(xa, wv0.z, acc[a][2]);
        acc[a][3] = fmaf(xa, wv0.w, acc[a][3]);
        acc[a][4] = fmaf(xa, wv1.x, acc[a][4]);
        acc[a][5] = fmaf(xa, wv1.y, acc[a][5]);
        acc[a][6] = fmaf(xa, wv1.z, acc[a][6]);
        acc[a][7] = fmaf(xa, wv1.w, acc[a][7]);
      }
    }
  }

  __syncthreads();   // all xs reads done (needed when ALIAS)
  #pragma unroll
  for (int a = 0; a < RT; ++a) {
    #pragma unroll
    for (int c4 = 0; c4 < 2; ++c4) {
      float4 hv;
      hv.x = tanhf(acc[a][c4 * 4 + 0] + b1v[to * 8 + c4 * 4 + 0]);
      hv.y = tanhf(acc[a][c4 * 4 + 1] + b1v[to * 8 + c4 * 4 + 1]);
      hv.z = tanhf(acc[a][c4 * 4 + 2] + b1v[to * 8 + c4 * 4 + 2]);
      hv.w = tanhf(acc[a][c4 * 4 + 3] + b1v[to * 8 + c4 * 4 + 3]);
      *(float4*)&htp[(tr * RT + a) * DHID + to * 8 + c4 * 4] = hv;
    }
  }
  __syncthreads();

  float acc2[RT][OT];
  #pragma unroll
  for (int a = 0; a < RT; ++a)
    #pragma unroll
    for (int c = 0; c < OT; ++c) acc2[a][c] = 0.f;

  for (int j = 0; j < DHID; j += 4) {
    float4 hv[RT];
    #pragma unroll
    for (int a = 0; a < RT; ++a)
      hv[a] = *(const float4*)&htp[(tr * RT + a) * DHID + j];
    #pragma unroll
    for (int jj = 0; jj < 4; ++jj) {
      const int jrow = j + jj;
      const int sw = (jrow & 7) << 2;
      #pragma unroll
      for (int c4 = 0; c4 < OT / 4; ++c4) {
        const float4 wv = *(const float4*)&w2t[jrow * DOUT + ((to * OT + c4 * 4) ^ sw)];
        #pragma unroll
        for (int a = 0; a < RT; ++a) {
          const float ha = reinterpret_cast<const float*>(&hv[a])[jj];
          acc2[a][c4 * 4 + 0] = fmaf(ha, wv.x, acc2[a][c4 * 4 + 0]);
          acc2[a][c4 * 4 + 1] = fmaf(ha, wv.y, acc2[a][c4 * 4 + 1]);
          acc2[a][c4 * 4 + 2] = fmaf(ha, wv.z, acc2[a][c4 * 4 + 2]);
          acc2[a][c4 * 4 + 3] = fmaf(ha, wv.w, acc2[a][c4 * 4 + 3]);
        }
      }
    }
  }

  #pragma unroll
  for (int a = 0; a < RT; ++a) {
    const int rg = row0 + tr * RT + a;
    size_t ooff;
    if constexpr (GATHER) {
      const int f = rg >> 8, b = rg & 255;
      const int t = TAUc * (f + 1);
      ooff = ((size_t)b * TT + t) * (size_t)DOUT;
    } else {
      ooff = (size_t)rg * DOUT;
    }
    #pragma unroll
    for (int c4 = 0; c4 < OT / 4; ++c4) {
      float4 ov;
      ov.x = tanhf(acc2[a][c4 * 4 + 0] + b2v[to * OT + c4 * 4 + 0]);
      ov.y = tanhf(acc2[a][c4 * 4 + 1] + b2v[to * OT + c4 * 4 + 1]);
      ov.z = tanhf(acc2[a][c4 * 4 + 2] + b2v[to * OT + c4 * 4 + 2]);
      ov.w = tanhf(acc2[a][c4 * 4 + 3] + b2v[to * OT + c4 * 4 + 3]);
      *(float4*)&out[ooff + to * OT + c4 * 4] = ov;
    }
  }
}

// =====================================================================
// Scan kernel v3: SEGMENT-PARALLEL. Teacher forcing fully replaces the
// state every TAU=25 steps, so the 1024-step chain decomposes into 41
// independent segments of <=25 steps. Grid = 256 batch x 41 segments =
// 10496 blocks -> ~7 blocks/CU resident (VGPR ~68), latency hidden by
// TLP instead of exposed on a 1-wave-per-SIMD critical path.
//
// Block = 4 waves (256 threads). Wave roles (L = lane, jh = w&1):
//   w0: output k=L,    jh=0      w1: output k=64+L, jh=1
//   w2: output k=64+L, jh=0      w3: output k=L,    jh=1
// Each lane: 64 W floats in VGPRs (half-row, no spill), replicated
// state pair (zA=z[L], zB=z[64+L]): mean = in-wave butterfly; both
// next-state components recomputed redundantly -> ONE lgkm-only
// s_barrier per step; global stores stay fire-and-forget.
// Segment s>=1 reads its start state from the encoder stash at zs slot
// t0=25s, then overwrites that slot at its first step (self-ordered:
// the store is after the first barrier, the stash read before it).
// =====================================================================
__global__ __launch_bounds__(256, 1) void scan_kernel(
    const float* __restrict__ AW, const float* __restrict__ z0,
    const float* __restrict__ hvec, const float* __restrict__ alphas,
    const float* __restrict__ thetas, float* __restrict__ zs)
{
  const int bid = blockIdx.x;
  const int b = bid & (BB - 1);
  const int s = bid >> 8;                 // segment 0..40
  const int t0 = s * TAUc;
  const int nsteps = (s == NSEG - 1) ? (TT - (NSEG - 1) * TAUc) : TAUc;

  const int tid = threadIdx.x;
  const int w = tid >> 6;
  const int L = tid & 63;
  const int jh = w & 1;                                // j-half for matvec
  const int k = ((w == 1) || (w == 2)) ? (64 + L) : L; // owned output
  const int c = jh * 64 + L;                           // basis component

  __shared__ float basis_w[4][64];   // per-wave private basis copy
  __shared__ float pl[2][2][128];    // [buf][jhalf][k] partial sums

  // --- W half-row in registers (diag removed) ---
  float Wreg[64];
  #pragma unroll 64
  for (int j = 0; j < 64; ++j) {
    const int jj = jh * 64 + j;
    Wreg[j] = (jj == k) ? 0.f : AW[k * DZc + jj];
  }
  const float aA = AW[L * DZc + L];
  const float aB = AW[(64 + L) * DZc + (64 + L)];
  const float hA = hvec[L];
  const float hB = hvec[64 + L];

  float al[DBc], th[DBc];
  #pragma unroll
  for (int d = 0; d < DBc; ++d) {
    al[d] = alphas[d];
    th[d] = thetas[c * DBc + d];
  }

  const size_t zbase = (size_t)b * TT * DZc;
  float zA, zB;
  if (s == 0) {
    zA = z0[b * DZc + L];
    zB = z0[b * DZc + 64 + L];
  } else {  // encoder stash (enc[t0]) — forcing state for iteration t0
    zA = zs[zbase + (size_t)t0 * DZc + L];
    zB = zs[zbase + (size_t)t0 * DZc + 64 + L];
  }

  for (int i = 0; i < nsteps; ++i) {
    const int t = t0 + i;

    // mean over 128 components: in-wave butterfly on pair sums
    float ssum = zA + zB;
    #pragma unroll
    for (int m = 1; m < 64; m <<= 1) ssum += __shfl_xor(ssum, m, 64);
    const float mean = ssum * (1.0f / 128.0f);

    // basis for this lane's component c
    const float zc = (jh ? zB : zA) - mean;
    float bsum = 0.f;
    #pragma unroll
    for (int d = 0; d < DBc; ++d)
      bsum = fmaf(al[d], fmaxf(zc + th[d], 0.f), bsum);
    basis_w[w][L] = bsum;     // wave-private; in-order DS RAW, lgkm only

    // half-row matvec, 4 independent accumulators
    float p0 = 0.f, p1 = 0.f, p2 = 0.f, p3 = 0.f;
    #pragma unroll
    for (int q = 0; q < 16; ++q) {
      const float4 bb = *(const float4*)&basis_w[w][q * 4];
      p0 = fmaf(bb.x, Wreg[q * 4 + 0], p0);
      p1 = fmaf(bb.y, Wreg[q * 4 + 1], p1);
      p2 = fmaf(bb.z, Wreg[q * 4 + 2], p2);
      p3 = fmaf(bb.w, Wreg[q * 4 + 3], p3);
    }
    const float p = (p0 + p1) + (p2 + p3);

    // publish partial, single lgkm-only barrier
    pl[i & 1][jh][k] = p;
    __asm__ volatile("s_waitcnt lgkmcnt(0)" ::: "memory");
    __builtin_amdgcn_s_barrier();
    __asm__ volatile("" ::: "memory");

    // every lane redundantly finishes BOTH components -> no 2nd barrier
    const float pA = pl[i & 1][0][L]      + pl[i & 1][1][L];
    const float pB = pl[i & 1][0][64 + L] + pl[i & 1][1][64 + L];
    float znA = fmaf(aA, zA, hA) + pA;
    float znB = fmaf(aB, zB, hB) + pB;
    znA = fminf(fmaxf(znA, -CLIPV), CLIPV);
    znB = fminf(fmaxf(znB, -CLIPV), CLIPV);

    // fire-and-forget store (waves 0/1 only)
    if (w == 0)      zs[zbase + (size_t)t * DZc + L]      = znA;
    else if (w == 1) zs[zbase + (size_t)t * DZc + 64 + L] = znB;

    zA = znA; zB = znB;
  }
}

extern "C" void kernel_launch(void* const* d_in, const int* in_sizes, int n_in,
                              void* d_out, int out_size, void* d_ws, size_t ws_size,
                              hipStream_t stream) {
  const float* x      = (const float*)d_in[0];
  const float* z0     = (const float*)d_in[1];
  const float* AW     = (const float*)d_in[2];
  const float* hvec   = (const float*)d_in[3];
  const float* alphas = (const float*)d_in[4];
  const float* thetas = (const float*)d_in[5];
  const float* ew1    = (const float*)d_in[6];
  const float* eb1    = (const float*)d_in[7];
  const float* ew2    = (const float*)d_in[8];
  const float* eb2    = (const float*)d_in[9];
  const float* dw1    = (const float*)d_in[10];
  const float* db1    = (const float*)d_in[11];
  const float* dw2    = (const float*)d_in[12];
  const float* db2    = (const float*)d_in[13];

  float* xp = (float*)d_out;                       // (B,T,DX)
  float* zs = xp + (size_t)BB * TT * DXc;          // (B,T,DZ)

  // 1) encoder at the 40 forcing timesteps -> stash into zs slots
  hipLaunchKernelGGL((mlp_kernel<DXc, DZc, DZc, 32, true, false>),
                     dim3(NF * BB / 32), dim3(256), 0, stream,
                     x, ew1, eb1, ew2, eb2, zs);

  // 2) recurrence scan: segment-parallel, 256 batch x 41 segments
  hipLaunchKernelGGL(scan_kernel, dim3(BB * NSEG), dim3(256), 0, stream,
                     AW, z0, hvec, alphas, thetas, zs);

  // 3) decoder over all (b,t)
  hipLaunchKernelGGL((mlp_kernel<DZc, DZc, DXc, 64, false, true>),
                     dim3(BB * TT / 64), dim3(256), 0, stream,
                     zs, dw1, db1, dw2, db2, xp);
}

// Round 4
// 473.473 us; speedup vs baseline: 2.9040x; 1.5883x over previous
//
#include <hip/hip_runtime.h>
#include <hip/hip_bf16.h>

// ---- problem constants ----
constexpr int BB  = 256;   // batch
constexpr int TT  = 1024;  // timesteps
constexpr int DXc = 64;
constexpr int DZc = 128;
constexpr int DBc = 16;
constexpr int TAUc = 25;
constexpr float CLIPV = 10.0f;
constexpr int NF = 40;     // forcing steps: t = 25..1000
constexpr int NSEG = 41;   // independent scan segments (forcing breaks chain)
constexpr int GRP = 16;    // batch rows per scan block (MFMA N dim)

typedef __attribute__((ext_vector_type(8))) short short8;   // 8 bf16 = 4 VGPR
typedef __attribute__((ext_vector_type(4))) float f32x4;
typedef __attribute__((ext_vector_type(4))) unsigned u32x4;

__device__ __forceinline__ unsigned perm_b32(unsigned a, unsigned b, unsigned s) {
  return __builtin_amdgcn_perm(a, b, s);
}

// =====================================================================
// Fused 2-layer tanh MLP (encoder/decoder) — unchanged this round.
// =====================================================================
template<int DIN, int DHID, int DOUT, int ROWS, bool GATHER, bool ALIAS>
__global__ __launch_bounds__(256, 1) void mlp_kernel(
    const float* __restrict__ in, const float* __restrict__ w1,
    const float* __restrict__ b1v, const float* __restrict__ w2,
    const float* __restrict__ b2v, float* __restrict__ out)
{
  static_assert(!ALIAS || DIN == DHID, "alias requires DIN==DHID");
  static_assert(DHID == 128, "layer1 tiling assumes DHID==128");
  constexpr int RT = ROWS / 16;
  constexpr int OT = DOUT / 16;

  __shared__ float w1t[DIN * DHID];
  __shared__ float w2t[DHID * DOUT];
  __shared__ float xs[ROWS * DIN];
  __shared__ float ht_sep[ALIAS ? 4 : ROWS * DHID];
  float* htp = ALIAS ? xs : ht_sep;

  const int tid = threadIdx.x;
  const int to = tid & 15, tr = tid >> 4;
  const int row0 = blockIdx.x * ROWS;

  for (int idx = tid; idx < DHID * DIN; idx += 256) {
    const int o = idx / DIN, i = idx - o * DIN;
    w1t[i * DHID + (o ^ ((i & 7) << 2))] = w1[idx];
  }
  for (int idx = tid; idx < DOUT * DHID; idx += 256) {
    const int o = idx / DHID, j = idx - o * DHID;
    w2t[j * DOUT + (o ^ ((j & 7) << 2))] = w2[idx];
  }
  for (int idx = tid; idx < ROWS * DIN; idx += 256) {
    const int r = idx / DIN, i = idx - r * DIN;
    const int rg = row0 + r;
    size_t off;
    if constexpr (GATHER) {
      const int f = rg >> 8, b = rg & 255;
      const int t = TAUc * (f + 1);
      off = ((size_t)b * TT + t) * (size_t)DIN;
    } else {
      off = (size_t)rg * DIN;
    }
    xs[idx] = in[off + i];
  }
  __syncthreads();

  float acc[RT][8];
  #pragma unroll
  for (int a = 0; a < RT; ++a)
    #pragma unroll
    for (int c = 0; c < 8; ++c) acc[a][c] = 0.f;

  for (int i = 0; i < DIN; i += 4) {
    float4 xv[RT];
    #pragma unroll
    for (int a = 0; a < RT; ++a)
      xv[a] = *(const float4*)&xs[(tr * RT + a) * DIN + i];
    #pragma unroll
    for (int ii = 0; ii < 4; ++ii) {
      const int irow = i + ii;
      const int sw = (irow & 7) << 2;
      const float4 wv0 = *(const float4*)&w1t[irow * DHID + ((to * 8 + 0) ^ sw)];
      const float4 wv1 = *(const float4*)&w1t[irow * DHID + ((to * 8 + 4) ^ sw)];
      #pragma unroll
      for (int a = 0; a < RT; ++a) {
        const float xa = reinterpret_cast<const float*>(&xv[a])[ii];
        acc[a][0] = fmaf(xa, wv0.x, acc[a][0]);
        acc[a][1] = fmaf(xa, wv0.y, acc[a][1]);
        acc[a][2] = fmaf(xa, wv0.z, acc[a][2]);
        acc[a][3] = fmaf(xa, wv0.w, acc[a][3]);
        acc[a][4] = fmaf(xa, wv1.x, acc[a][4]);
        acc[a][5] = fmaf(xa, wv1.y, acc[a][5]);
        acc[a][6] = fmaf(xa, wv1.z, acc[a][6]);
        acc[a][7] = fmaf(xa, wv1.w, acc[a][7]);
      }
    }
  }

  __syncthreads();
  #pragma unroll
  for (int a = 0; a < RT; ++a) {
    #pragma unroll
    for (int c4 = 0; c4 < 2; ++c4) {
      float4 hv;
      hv.x = tanhf(acc[a][c4 * 4 + 0] + b1v[to * 8 + c4 * 4 + 0]);
      hv.y = tanhf(acc[a][c4 * 4 + 1] + b1v[to * 8 + c4 * 4 + 1]);
      hv.z = tanhf(acc[a][c4 * 4 + 2] + b1v[to * 8 + c4 * 4 + 2]);
      hv.w = tanhf(acc[a][c4 * 4 + 3] + b1v[to * 8 + c4 * 4 + 3]);
      *(float4*)&htp[(tr * RT + a) * DHID + to * 8 + c4 * 4] = hv;
    }
  }
  __syncthreads();

  float acc2[RT][OT];
  #pragma unroll
  for (int a = 0; a < RT; ++a)
    #pragma unroll
    for (int c = 0; c < OT; ++c) acc2[a][c] = 0.f;

  for (int j = 0; j < DHID; j += 4) {
    float4 hv[RT];
    #pragma unroll
    for (int a = 0; a < RT; ++a)
      hv[a] = *(const float4*)&htp[(tr * RT + a) * DHID + j];
    #pragma unroll
    for (int jj = 0; jj < 4; ++jj) {
      const int jrow = j + jj;
      const int sw = (jrow & 7) << 2;
      #pragma unroll
      for (int c4 = 0; c4 < OT / 4; ++c4) {
        const float4 wv = *(const float4*)&w2t[jrow * DOUT + ((to * OT + c4 * 4) ^ sw)];
        #pragma unroll
        for (int a = 0; a < RT; ++a) {
          const float ha = reinterpret_cast<const float*>(&hv[a])[jj];
          acc2[a][c4 * 4 + 0] = fmaf(ha, wv.x, acc2[a][c4 * 4 + 0]);
          acc2[a][c4 * 4 + 1] = fmaf(ha, wv.y, acc2[a][c4 * 4 + 1]);
          acc2[a][c4 * 4 + 2] = fmaf(ha, wv.z, acc2[a][c4 * 4 + 2]);
          acc2[a][c4 * 4 + 3] = fmaf(ha, wv.w, acc2[a][c4 * 4 + 3]);
        }
      }
    }
  }

  #pragma unroll
  for (int a = 0; a < RT; ++a) {
    const int rg = row0 + tr * RT + a;
    size_t ooff;
    if constexpr (GATHER) {
      const int f = rg >> 8, b = rg & 255;
      const int t = TAUc * (f + 1);
      ooff = ((size_t)b * TT + t) * (size_t)DOUT;
    } else {
      ooff = (size_t)rg * DOUT;
    }
    #pragma unroll
    for (int c4 = 0; c4 < OT / 4; ++c4) {
      float4 ov;
      ov.x = tanhf(acc2[a][c4 * 4 + 0] + b2v[to * OT + c4 * 4 + 0]);
      ov.y = tanhf(acc2[a][c4 * 4 + 1] + b2v[to * OT + c4 * 4 + 1]);
      ov.z = tanhf(acc2[a][c4 * 4 + 2] + b2v[to * OT + c4 * 4 + 2]);
      ov.w = tanhf(acc2[a][c4 * 4 + 3] + b2v[to * OT + c4 * 4 + 3]);
      *(float4*)&out[ooff + to * OT + c4 * 4] = ov;
    }
  }
}

// =====================================================================
// Scan v4: MFMA, 16 batch rows per block x 41 segments (grid 656).
// Per step: z_next[128cx16r] = diag(A)*z + h + W @ basis, via
// mfma_f32_16x16x32_bf16 with W stationary in VGPR frags (hi/lo bf16
// split, 3-term product => ~1e-5 rel err). Two thread roles per step:
//   frag-lane (l=tid&63, w=tid>>6): C/D frags, owns comps
//     (2w+tm)*16 + (l>>4)*4 + j  of batch-row  g*16 + (l&15)
//   basis-lane (cb=tid>>1, rh=tid&1): computes basis for comp cb,
//     rows rh*8..rh*8+7  (th[16] per comp stays in registers)
// 2 lgkm-only barriers/step; z_seq stores fire-and-forget.
// =====================================================================
__global__ __launch_bounds__(256, 1) void scan_mfma_kernel(
    const float* __restrict__ AW, const float* __restrict__ z0,
    const float* __restrict__ hvec, const float* __restrict__ alphas,
    const float* __restrict__ thetas, float* __restrict__ zs)
{
  const int bid = blockIdx.x;
  const int g = bid & 15;               // row group (16 groups of 16)
  const int s = bid >> 4;               // segment 0..40
  const int t0 = s * TAUc;
  const int nsteps = (s == NSEG - 1) ? (TT - t0) : TAUc;

  const int tid = threadIdx.x;
  const int w = tid >> 6, l = tid & 63;
  const int rowf = l & 15;              // MFMA N index = row within group
  const int kg = l >> 4;                // 0..3

  __shared__ float zbuf[DZc][20];       // [comp][row], pitch 20 (aligned+spread)
  __shared__ float meanp[16][4];        // [row][wave] partial sums
  __shared__ unsigned pbuf[16][DZc];    // [row][comp^swz] packed bf16 (hi|lo<<16)

  // ---- stationary data: W A-frags (hi/lo), diag, h, thetas, alphas ----
  short8 Whi[2][4], Wlo[2][4];
  #pragma unroll
  for (int tm = 0; tm < 2; ++tm) {
    const int m = (2 * w + tm) * 16 + rowf;         // M index = comp
    #pragma unroll
    for (int kt = 0; kt < 4; ++kt) {
      const int kb = kt * 32 + kg * 8;
      float f[8];
      #pragma unroll
      for (int i = 0; i < 8; ++i) {
        const int k = kb + i;
        f[i] = (k == m) ? 0.f : AW[m * DZc + k];    // diag removed
      }
      u32x4 hi4, lo4;
      #pragma unroll
      for (int p = 0; p < 4; ++p) {
        const unsigned b0 = __float_as_uint(f[2 * p]);
        const unsigned b1 = __float_as_uint(f[2 * p + 1]);
        hi4[p] = perm_b32(b1, b0, 0x07060302u);     // top16(f0)|top16(f1)<<16
        const float l0 = f[2 * p]     - __uint_as_float(b0 & 0xFFFF0000u);
        const float l1 = f[2 * p + 1] - __uint_as_float(b1 & 0xFFFF0000u);
        lo4[p] = perm_b32(__float_as_uint(l1), __float_as_uint(l0), 0x07060302u);
      }
      Whi[tm][kt] = __builtin_bit_cast(short8, hi4);
      Wlo[tm][kt] = __builtin_bit_cast(short8, lo4);
    }
  }
  float a_d[2][4], h_d[2][4];
  #pragma unroll
  for (int tm = 0; tm < 2; ++tm)
    #pragma unroll
    for (int j = 0; j < 4; ++j) {
      const int comp = (2 * w + tm) * 16 + kg * 4 + j;
      a_d[tm][j] = AW[comp * DZc + comp];
      h_d[tm][j] = hvec[comp];
    }

  const int cb = tid >> 1;              // basis comp 0..127
  const int rh = tid & 1;               // row half
  float th[DBc], al[DBc];
  #pragma unroll
  for (int d = 0; d < DBc; ++d) {
    th[d] = thetas[cb * DBc + d];
    al[d] = alphas[d];
  }

  // ---- init z (C/D frag layout) ----
  const int brow = g * GRP + rowf;
  const size_t zb_row = (size_t)brow * TT * DZc;
  f32x4 z[2];
  #pragma unroll
  for (int tm = 0; tm < 2; ++tm) {
    const int comp0 = (2 * w + tm) * 16 + kg * 4;
    if (s == 0) z[tm] = *(const f32x4*)&z0[brow * DZc + comp0];
    else        z[tm] = *(const f32x4*)&zs[zb_row + (size_t)t0 * DZc + comp0];
  }

#define SCAN_BAR() do { \
    __asm__ volatile("s_waitcnt lgkmcnt(0)" ::: "memory"); \
    __builtin_amdgcn_s_barrier(); \
    __asm__ volatile("" ::: "memory"); } while (0)

  for (int it = 0; it < nsteps; ++it) {
    const int t = t0 + it;

    // ---- Phase A: publish z + row-sum partials ----
    float ssum = ((z[0][0] + z[0][1]) + (z[0][2] + z[0][3]))
               + ((z[1][0] + z[1][1]) + (z[1][2] + z[1][3]));
    ssum += __shfl_xor(ssum, 16, 64);
    ssum += __shfl_xor(ssum, 32, 64);   // sum of this wave's 32 comps, row rowf
    if (l < 16) meanp[l][w] = ssum;
    #pragma unroll
    for (int tm = 0; tm < 2; ++tm)
      #pragma unroll
      for (int j = 0; j < 4; ++j)
        zbuf[(2 * w + tm) * 16 + kg * 4 + j][rowf] = z[tm][j];
    SCAN_BAR();

    // ---- Phase B: basis for comp cb, rows rh*8..+7 ----
    float zr[8], mean[8];
    *(f32x4*)&zr[0] = *(const f32x4*)&zbuf[cb][rh * 8];
    *(f32x4*)&zr[4] = *(const f32x4*)&zbuf[cb][rh * 8 + 4];
    #pragma unroll
    for (int q = 0; q < 8; ++q) {
      const f32x4 mp = *(const f32x4*)&meanp[rh * 8 + q][0];
      mean[q] = ((mp[0] + mp[1]) + (mp[2] + mp[3])) * (1.0f / 128.0f);
    }
    #pragma unroll
    for (int q = 0; q < 8; ++q) {
      const float zc = zr[q] - mean[q];
      float bs = 0.f;
      #pragma unroll
      for (int d = 0; d < DBc; ++d)
        bs = fmaf(al[d], fmaxf(zc + th[d], 0.f), bs);
      const unsigned fb = __float_as_uint(bs);
      const float lof = bs - __uint_as_float(fb & 0xFFFF0000u);
      const unsigned pk = perm_b32(__float_as_uint(lof), fb, 0x07060302u);
      const int r = rh * 8 + q;
      pbuf[r][cb ^ ((r & 3) << 3)] = pk;      // XOR swizzle (4-way max)
    }
    SCAN_BAR();

    // ---- Phase C: B-frags + MFMA (bf16x3) ----
    f32x4 acc1[2], acc2[2];
    #pragma unroll
    for (int tm = 0; tm < 2; ++tm) {
      #pragma unroll
      for (int j = 0; j < 4; ++j) {
        acc1[tm][j] = fmaf(a_d[tm][j], z[tm][j], h_d[tm][j]);
        acc2[tm][j] = 0.f;
      }
    }
    #pragma unroll
    for (int kt = 0; kt < 4; ++kt) {
      const int cbase = (kt * 32 + kg * 8) ^ ((rowf & 3) << 3);
      const u32x4 p0 = *(const u32x4*)&pbuf[rowf][cbase];
      const u32x4 p1 = *(const u32x4*)&pbuf[rowf][cbase + 4];
      u32x4 hi4, lo4;
      hi4[0] = perm_b32(p0[1], p0[0], 0x05040100u);
      hi4[1] = perm_b32(p0[3], p0[2], 0x05040100u);
      hi4[2] = perm_b32(p1[1], p1[0], 0x05040100u);
      hi4[3] = perm_b32(p1[3], p1[2], 0x05040100u);
      lo4[0] = perm_b32(p0[1], p0[0], 0x07060302u);
      lo4[1] = perm_b32(p0[3], p0[2], 0x07060302u);
      lo4[2] = perm_b32(p1[1], p1[0], 0x07060302u);
      lo4[3] = perm_b32(p1[3], p1[2], 0x07060302u);
      const short8 Bhi = __builtin_bit_cast(short8, hi4);
      const short8 Blo = __builtin_bit_cast(short8, lo4);
      acc1[0] = __builtin_amdgcn_mfma_f32_16x16x32_bf16(Whi[0][kt], Bhi, acc1[0], 0, 0, 0);
      acc1[1] = __builtin_amdgcn_mfma_f32_16x16x32_bf16(Whi[1][kt], Bhi, acc1[1], 0, 0, 0);
      acc2[0] = __builtin_amdgcn_mfma_f32_16x16x32_bf16(Whi[0][kt], Blo, acc2[0], 0, 0, 0);
      acc2[0] = __builtin_amdgcn_mfma_f32_16x16x32_bf16(Wlo[0][kt], Bhi, acc2[0], 0, 0, 0);
      acc2[1] = __builtin_amdgcn_mfma_f32_16x16x32_bf16(Whi[1][kt], Blo, acc2[1], 0, 0, 0);
      acc2[1] = __builtin_amdgcn_mfma_f32_16x16x32_bf16(Wlo[1][kt], Bhi, acc2[1], 0, 0, 0);
    }
    #pragma unroll
    for (int tm = 0; tm < 2; ++tm) {
      f32x4 zn;
      #pragma unroll
      for (int j = 0; j < 4; ++j) {
        float v = acc1[tm][j] + acc2[tm][j];
        zn[j] = fminf(fmaxf(v, -CLIPV), CLIPV);
      }
      *(f32x4*)&zs[zb_row + (size_t)t * DZc + (2 * w + tm) * 16 + kg * 4] = zn;
      z[tm] = zn;   // loop-carried state
    }
  }
#undef SCAN_BAR
}

extern "C" void kernel_launch(void* const* d_in, const int* in_sizes, int n_in,
                              void* d_out, int out_size, void* d_ws, size_t ws_size,
                              hipStream_t stream) {
  const float* x      = (const float*)d_in[0];
  const float* z0     = (const float*)d_in[1];
  const float* AW     = (const float*)d_in[2];
  const float* hvec   = (const float*)d_in[3];
  const float* alphas = (const float*)d_in[4];
  const float* thetas = (const float*)d_in[5];
  const float* ew1    = (const float*)d_in[6];
  const float* eb1    = (const float*)d_in[7];
  const float* ew2    = (const float*)d_in[8];
  const float* eb2    = (const float*)d_in[9];
  const float* dw1    = (const float*)d_in[10];
  const float* db1    = (const float*)d_in[11];
  const float* dw2    = (const float*)d_in[12];
  const float* db2    = (const float*)d_in[13];

  float* xp = (float*)d_out;                       // (B,T,DX)
  float* zs = xp + (size_t)BB * TT * DXc;          // (B,T,DZ)

  // 1) encoder at the 40 forcing timesteps -> stash into zs slots
  hipLaunchKernelGGL((mlp_kernel<DXc, DZc, DZc, 32, true, false>),
                     dim3(NF * BB / 32), dim3(256), 0, stream,
                     x, ew1, eb1, ew2, eb2, zs);

  // 2) recurrence scan: MFMA, 16-row groups x 41 segments
  hipLaunchKernelGGL(scan_mfma_kernel, dim3((BB / GRP) * NSEG), dim3(256), 0, stream,
                     AW, z0, hvec, alphas, thetas, zs);

  // 3) decoder over all (b,t)
  hipLaunchKernelGGL((mlp_kernel<DZc, DZc, DXc, 64, false, true>),
                     dim3(BB * TT / 64), dim3(256), 0, stream,
                     zs, dw1, db1, dw2, db2, xp);
}

// Round 5
// 233.191 us; speedup vs baseline: 5.8964x; 2.0304x over previous
//
#include <hip/hip_runtime.h>
#include <hip/hip_bf16.h>

// ---- problem constants ----
constexpr int BB  = 256;   // batch
constexpr int TT  = 1024;  // timesteps
constexpr int DXc = 64;
constexpr int DZc = 128;
constexpr int DBc = 16;
constexpr int TAUc = 25;
constexpr float CLIPV = 10.0f;
constexpr int NF = 40;     // forcing steps: t = 25..1000
constexpr int NSEG = 41;   // independent scan segments (forcing breaks chain)
constexpr int GRP = 16;    // batch rows per scan block (MFMA N dim)

typedef __attribute__((ext_vector_type(8))) short short8;   // 8 bf16 = 4 VGPR
typedef __attribute__((ext_vector_type(4))) float f32x4;
typedef __attribute__((ext_vector_type(4))) unsigned u32x4;

__device__ __forceinline__ unsigned perm_b32(unsigned a, unsigned b, unsigned s) {
  return __builtin_amdgcn_perm(a, b, s);
}

// pack 8 floats (a0..3,b0..3) into bf16 hi + residual-lo short8 frags
__device__ __forceinline__ void pack_hilo8(const f32x4 a, const f32x4 b,
                                           short8& hi, short8& lo) {
  float f[8];
  *(f32x4*)&f[0] = a;
  *(f32x4*)&f[4] = b;
  u32x4 hi4, lo4;
  #pragma unroll
  for (int p = 0; p < 4; ++p) {
    const unsigned b0 = __float_as_uint(f[2 * p]);
    const unsigned b1 = __float_as_uint(f[2 * p + 1]);
    hi4[p] = perm_b32(b1, b0, 0x07060302u);     // hi16(f0) | hi16(f1)<<16
    const float l0 = f[2 * p]     - __uint_as_float(b0 & 0xFFFF0000u);
    const float l1 = f[2 * p + 1] - __uint_as_float(b1 & 0xFFFF0000u);
    lo4[p] = perm_b32(__float_as_uint(l1), __float_as_uint(l0), 0x07060302u);
  }
  hi = __builtin_bit_cast(short8, hi4);
  lo = __builtin_bit_cast(short8, lo4);
}

// fast tanh: 1 - 2/(1+exp2(2|x|*log2e)), copysign. ~6 VALU, ~1e-6 rel err.
__device__ __forceinline__ float ftanh(float x) {
  const float ax = __builtin_fabsf(x);
  const float p  = __builtin_amdgcn_exp2f(ax * 2.8853900817779268f);
  const float r  = __builtin_amdgcn_rcpf(p + 1.0f);
  const float t  = __builtin_fmaf(-2.0f, r, 1.0f);
  return __builtin_copysignf(t, x);
}

#define SCAN_BAR() do { \
    __asm__ volatile("s_waitcnt lgkmcnt(0)" ::: "memory"); \
    __builtin_amdgcn_s_barrier(); \
    __asm__ volatile("" ::: "memory"); } while (0)

// =====================================================================
// Fused 2-layer tanh MLP — now used for the ENCODER only (small: 40x256
// rows). Unchanged.
// =====================================================================
template<int DIN, int DHID, int DOUT, int ROWS, bool GATHER, bool ALIAS>
__global__ __launch_bounds__(256, 1) void mlp_kernel(
    const float* __restrict__ in, const float* __restrict__ w1,
    const float* __restrict__ b1v, const float* __restrict__ w2,
    const float* __restrict__ b2v, float* __restrict__ out)
{
  static_assert(!ALIAS || DIN == DHID, "alias requires DIN==DHID");
  static_assert(DHID == 128, "layer1 tiling assumes DHID==128");
  constexpr int RT = ROWS / 16;
  constexpr int OT = DOUT / 16;

  __shared__ float w1t[DIN * DHID];
  __shared__ float w2t[DHID * DOUT];
  __shared__ float xs[ROWS * DIN];
  __shared__ float ht_sep[ALIAS ? 4 : ROWS * DHID];
  float* htp = ALIAS ? xs : ht_sep;

  const int tid = threadIdx.x;
  const int to = tid & 15, tr = tid >> 4;
  const int row0 = blockIdx.x * ROWS;

  for (int idx = tid; idx < DHID * DIN; idx += 256) {
    const int o = idx / DIN, i = idx - o * DIN;
    w1t[i * DHID + (o ^ ((i & 7) << 2))] = w1[idx];
  }
  for (int idx = tid; idx < DOUT * DHID; idx += 256) {
    const int o = idx / DHID, j = idx - o * DHID;
    w2t[j * DOUT + (o ^ ((j & 7) << 2))] = w2[idx];
  }
  for (int idx = tid; idx < ROWS * DIN; idx += 256) {
    const int r = idx / DIN, i = idx - r * DIN;
    const int rg = row0 + r;
    size_t off;
    if constexpr (GATHER) {
      const int f = rg >> 8, b = rg & 255;
      const int t = TAUc * (f + 1);
      off = ((size_t)b * TT + t) * (size_t)DIN;
    } else {
      off = (size_t)rg * DIN;
    }
    xs[idx] = in[off + i];
  }
  __syncthreads();

  float acc[RT][8];
  #pragma unroll
  for (int a = 0; a < RT; ++a)
    #pragma unroll
    for (int c = 0; c < 8; ++c) acc[a][c] = 0.f;

  for (int i = 0; i < DIN; i += 4) {
    float4 xv[RT];
    #pragma unroll
    for (int a = 0; a < RT; ++a)
      xv[a] = *(const float4*)&xs[(tr * RT + a) * DIN + i];
    #pragma unroll
    for (int ii = 0; ii < 4; ++ii) {
      const int irow = i + ii;
      const int sw = (irow & 7) << 2;
      const float4 wv0 = *(const float4*)&w1t[irow * DHID + ((to * 8 + 0) ^ sw)];
      const float4 wv1 = *(const float4*)&w1t[irow * DHID + ((to * 8 + 4) ^ sw)];
      #pragma unroll
      for (int a = 0; a < RT; ++a) {
        const float xa = reinterpret_cast<const float*>(&xv[a])[ii];
        acc[a][0] = fmaf(xa, wv0.x, acc[a][0]);
        acc[a][1] = fmaf(xa, wv0.y, acc[a][1]);
        acc[a][2] = fmaf(xa, wv0.z, acc[a][2]);
        acc[a][3] = fmaf(xa, wv0.w, acc[a][3]);
        acc[a][4] = fmaf(xa, wv1.x, acc[a][4]);
        acc[a][5] = fmaf(xa, wv1.y, acc[a][5]);
        acc[a][6] = fmaf(xa, wv1.z, acc[a][6]);
        acc[a][7] = fmaf(xa, wv1.w, acc[a][7]);
      }
    }
  }

  __syncthreads();
  #pragma unroll
  for (int a = 0; a < RT; ++a) {
    #pragma unroll
    for (int c4 = 0; c4 < 2; ++c4) {
      float4 hv;
      hv.x = tanhf(acc[a][c4 * 4 + 0] + b1v[to * 8 + c4 * 4 + 0]);
      hv.y = tanhf(acc[a][c4 * 4 + 1] + b1v[to * 8 + c4 * 4 + 1]);
      hv.z = tanhf(acc[a][c4 * 4 + 2] + b1v[to * 8 + c4 * 4 + 2]);
      hv.w = tanhf(acc[a][c4 * 4 + 3] + b1v[to * 8 + c4 * 4 + 3]);
      *(float4*)&htp[(tr * RT + a) * DHID + to * 8 + c4 * 4] = hv;
    }
  }
  __syncthreads();

  float acc2[RT][OT];
  #pragma unroll
  for (int a = 0; a < RT; ++a)
    #pragma unroll
    for (int c = 0; c < OT; ++c) acc2[a][c] = 0.f;

  for (int j = 0; j < DHID; j += 4) {
    float4 hv[RT];
    #pragma unroll
    for (int a = 0; a < RT; ++a)
      hv[a] = *(const float4*)&htp[(tr * RT + a) * DHID + j];
    #pragma unroll
    for (int jj = 0; jj < 4; ++jj) {
      const int jrow = j + jj;
      const int sw = (jrow & 7) << 2;
      #pragma unroll
      for (int c4 = 0; c4 < OT / 4; ++c4) {
        const float4 wv = *(const float4*)&w2t[jrow * DOUT + ((to * OT + c4 * 4) ^ sw)];
        #pragma unroll
        for (int a = 0; a < RT; ++a) {
          const float ha = reinterpret_cast<const float*>(&hv[a])[jj];
          acc2[a][c4 * 4 + 0] = fmaf(ha, wv.x, acc2[a][c4 * 4 + 0]);
          acc2[a][c4 * 4 + 1] = fmaf(ha, wv.y, acc2[a][c4 * 4 + 1]);
          acc2[a][c4 * 4 + 2] = fmaf(ha, wv.z, acc2[a][c4 * 4 + 2]);
          acc2[a][c4 * 4 + 3] = fmaf(ha, wv.w, acc2[a][c4 * 4 + 3]);
        }
      }
    }
  }

  #pragma unroll
  for (int a = 0; a < RT; ++a) {
    const int rg = row0 + tr * RT + a;
    size_t ooff;
    if constexpr (GATHER) {
      const int f = rg >> 8, b = rg & 255;
      const int t = TAUc * (f + 1);
      ooff = ((size_t)b * TT + t) * (size_t)DOUT;
    } else {
      ooff = (size_t)rg * DOUT;
    }
    #pragma unroll
    for (int c4 = 0; c4 < OT / 4; ++c4) {
      float4 ov;
      ov.x = tanhf(acc2[a][c4 * 4 + 0] + b2v[to * OT + c4 * 4 + 0]);
      ov.y = tanhf(acc2[a][c4 * 4 + 1] + b2v[to * OT + c4 * 4 + 1]);
      ov.z = tanhf(acc2[a][c4 * 4 + 2] + b2v[to * OT + c4 * 4 + 2]);
      ov.w = tanhf(acc2[a][c4 * 4 + 3] + b2v[to * OT + c4 * 4 + 3]);
      *(float4*)&out[ooff + to * OT + c4 * 4] = ov;
    }
  }
}

// =====================================================================
// Scan v4 (unchanged, validated): MFMA, 16 batch rows x 41 segments.
// =====================================================================
__global__ __launch_bounds__(256, 1) void scan_mfma_kernel(
    const float* __restrict__ AW, const float* __restrict__ z0,
    const float* __restrict__ hvec, const float* __restrict__ alphas,
    const float* __restrict__ thetas, float* __restrict__ zs)
{
  const int bid = blockIdx.x;
  const int g = bid & 15;
  const int s = bid >> 4;
  const int t0 = s * TAUc;
  const int nsteps = (s == NSEG - 1) ? (TT - t0) : TAUc;

  const int tid = threadIdx.x;
  const int w = tid >> 6, l = tid & 63;
  const int rowf = l & 15;
  const int kg = l >> 4;

  __shared__ float zbuf[DZc][20];
  __shared__ float meanp[16][4];
  __shared__ unsigned pbuf[16][DZc];

  short8 Whi[2][4], Wlo[2][4];
  #pragma unroll
  for (int tm = 0; tm < 2; ++tm) {
    const int m = (2 * w + tm) * 16 + rowf;
    #pragma unroll
    for (int kt = 0; kt < 4; ++kt) {
      const int kb = kt * 32 + kg * 8;
      float f[8];
      #pragma unroll
      for (int i = 0; i < 8; ++i) {
        const int k = kb + i;
        f[i] = (k == m) ? 0.f : AW[m * DZc + k];
      }
      pack_hilo8(*(const f32x4*)&f[0], *(const f32x4*)&f[4],
                 Whi[tm][kt], Wlo[tm][kt]);
    }
  }
  float a_d[2][4], h_d[2][4];
  #pragma unroll
  for (int tm = 0; tm < 2; ++tm)
    #pragma unroll
    for (int j = 0; j < 4; ++j) {
      const int comp = (2 * w + tm) * 16 + kg * 4 + j;
      a_d[tm][j] = AW[comp * DZc + comp];
      h_d[tm][j] = hvec[comp];
    }

  const int cb = tid >> 1;
  const int rh = tid & 1;
  float th[DBc], al[DBc];
  #pragma unroll
  for (int d = 0; d < DBc; ++d) {
    th[d] = thetas[cb * DBc + d];
    al[d] = alphas[d];
  }

  const int brow = g * GRP + rowf;
  const size_t zb_row = (size_t)brow * TT * DZc;
  f32x4 z[2];
  #pragma unroll
  for (int tm = 0; tm < 2; ++tm) {
    const int comp0 = (2 * w + tm) * 16 + kg * 4;
    if (s == 0) z[tm] = *(const f32x4*)&z0[brow * DZc + comp0];
    else        z[tm] = *(const f32x4*)&zs[zb_row + (size_t)t0 * DZc + comp0];
  }

  for (int it = 0; it < nsteps; ++it) {
    const int t = t0 + it;

    float ssum = ((z[0][0] + z[0][1]) + (z[0][2] + z[0][3]))
               + ((z[1][0] + z[1][1]) + (z[1][2] + z[1][3]));
    ssum += __shfl_xor(ssum, 16, 64);
    ssum += __shfl_xor(ssum, 32, 64);
    if (l < 16) meanp[l][w] = ssum;
    #pragma unroll
    for (int tm = 0; tm < 2; ++tm)
      #pragma unroll
      for (int j = 0; j < 4; ++j)
        zbuf[(2 * w + tm) * 16 + kg * 4 + j][rowf] = z[tm][j];
    SCAN_BAR();

    float zr[8], mean[8];
    *(f32x4*)&zr[0] = *(const f32x4*)&zbuf[cb][rh * 8];
    *(f32x4*)&zr[4] = *(const f32x4*)&zbuf[cb][rh * 8 + 4];
    #pragma unroll
    for (int q = 0; q < 8; ++q) {
      const f32x4 mp = *(const f32x4*)&meanp[rh * 8 + q][0];
      mean[q] = ((mp[0] + mp[1]) + (mp[2] + mp[3])) * (1.0f / 128.0f);
    }
    #pragma unroll
    for (int q = 0; q < 8; ++q) {
      const float zc = zr[q] - mean[q];
      float bs = 0.f;
      #pragma unroll
      for (int d = 0; d < DBc; ++d)
        bs = fmaf(al[d], fmaxf(zc + th[d], 0.f), bs);
      const unsigned fb = __float_as_uint(bs);
      const float lof = bs - __uint_as_float(fb & 0xFFFF0000u);
      const unsigned pk = perm_b32(__float_as_uint(lof), fb, 0x07060302u);
      const int r = rh * 8 + q;
      pbuf[r][cb ^ ((r & 3) << 3)] = pk;
    }
    SCAN_BAR();

    f32x4 acc1[2], acc2[2];
    #pragma unroll
    for (int tm = 0; tm < 2; ++tm) {
      #pragma unroll
      for (int j = 0; j < 4; ++j) {
        acc1[tm][j] = fmaf(a_d[tm][j], z[tm][j], h_d[tm][j]);
        acc2[tm][j] = 0.f;
      }
    }
    #pragma unroll
    for (int kt = 0; kt < 4; ++kt) {
      const int cbase = (kt * 32 + kg * 8) ^ ((rowf & 3) << 3);
      const u32x4 p0 = *(const u32x4*)&pbuf[rowf][cbase];
      const u32x4 p1 = *(const u32x4*)&pbuf[rowf][cbase + 4];
      u32x4 hi4, lo4;
      hi4[0] = perm_b32(p0[1], p0[0], 0x05040100u);
      hi4[1] = perm_b32(p0[3], p0[2], 0x05040100u);
      hi4[2] = perm_b32(p1[1], p1[0], 0x05040100u);
      hi4[3] = perm_b32(p1[3], p1[2], 0x05040100u);
      lo4[0] = perm_b32(p0[1], p0[0], 0x07060302u);
      lo4[1] = perm_b32(p0[3], p0[2], 0x07060302u);
      lo4[2] = perm_b32(p1[1], p1[0], 0x07060302u);
      lo4[3] = perm_b32(p1[3], p1[2], 0x07060302u);
      const short8 Bhi = __builtin_bit_cast(short8, hi4);
      const short8 Blo = __builtin_bit_cast(short8, lo4);
      acc1[0] = __builtin_amdgcn_mfma_f32_16x16x32_bf16(Whi[0][kt], Bhi, acc1[0], 0, 0, 0);
      acc1[1] = __builtin_amdgcn_mfma_f32_16x16x32_bf16(Whi[1][kt], Bhi, acc1[1], 0, 0, 0);
      acc2[0] = __builtin_amdgcn_mfma_f32_16x16x32_bf16(Whi[0][kt], Blo, acc2[0], 0, 0, 0);
      acc2[0] = __builtin_amdgcn_mfma_f32_16x16x32_bf16(Wlo[0][kt], Bhi, acc2[0], 0, 0, 0);
      acc2[1] = __builtin_amdgcn_mfma_f32_16x16x32_bf16(Whi[1][kt], Blo, acc2[1], 0, 0, 0);
      acc2[1] = __builtin_amdgcn_mfma_f32_16x16x32_bf16(Wlo[1][kt], Bhi, acc2[1], 0, 0, 0);
    }
    #pragma unroll
    for (int tm = 0; tm < 2; ++tm) {
      f32x4 zn;
      #pragma unroll
      for (int j = 0; j < 4; ++j) {
        float v = acc1[tm][j] + acc2[tm][j];
        zn[j] = fminf(fmaxf(v, -CLIPV), CLIPV);
      }
      *(f32x4*)&zs[zb_row + (size_t)t * DZc + (2 * w + tm) * 16 + kg * 4] = zn;
      z[tm] = zn;
    }
  }
}

// =====================================================================
// Decoder v2: MFMA, weights stationary in VGPR fragments (bf16 hi/lo,
// 3-term product). 4 waves/block; wave w owns layer1 comps
// [2w*16,(2w+2)*16) (2 M-tiles) and layer2 comps [w*16,(w+1)*16).
// 16-row tiles, DEC_NT tiles per block. h crosses waves via a
// double-buffered packed-u32 LDS buffer (XOR swizzle, <=4-way);
// ONE lgkm-only barrier per tile.
// =====================================================================
constexpr int DEC_NT = 16;                       // tiles (of 16 rows) per block

__global__ __launch_bounds__(256, 2) void dec_mfma_kernel(
    const float* __restrict__ zs, const float* __restrict__ w1,
    const float* __restrict__ b1v, const float* __restrict__ w2,
    const float* __restrict__ b2v, float* __restrict__ out)
{
  const int tid = threadIdx.x;
  const int w = tid >> 6, l = tid & 63;
  const int rowf = l & 15;                       // MFMA N index (row in tile)
  const int kg = l >> 4;                         // 0..3
  const int swz = (rowf & 3) << 3;

  __shared__ unsigned pbuf[2][16][DZc];          // [buf][row][comp^swz] hi|lo<<16

  // ---- stationary weight fragments ----
  short8 W1hi[2][4], W1lo[2][4], W2hi[4], W2lo[4];
  #pragma unroll
  for (int tm = 0; tm < 2; ++tm) {
    const int m = (2 * w + tm) * 16 + rowf;
    #pragma unroll
    for (int kt = 0; kt < 4; ++kt) {
      const int k0 = kt * 32 + kg * 8;
      pack_hilo8(*(const f32x4*)&w1[m * DZc + k0],
                 *(const f32x4*)&w1[m * DZc + k0 + 4],
                 W1hi[tm][kt], W1lo[tm][kt]);
    }
  }
  {
    const int m2 = w * 16 + rowf;
    #pragma unroll
    for (int kt = 0; kt < 4; ++kt) {
      const int k0 = kt * 32 + kg * 8;
      pack_hilo8(*(const f32x4*)&w2[m2 * DZc + k0],
                 *(const f32x4*)&w2[m2 * DZc + k0 + 4],
                 W2hi[kt], W2lo[kt]);
    }
  }
  float b1r[2][4], b2r[4];
  #pragma unroll
  for (int tm = 0; tm < 2; ++tm)
    #pragma unroll
    for (int j = 0; j < 4; ++j)
      b1r[tm][j] = b1v[(2 * w + tm) * 16 + kg * 4 + j];
  #pragma unroll
  for (int j = 0; j < 4; ++j)
    b2r[j] = b2v[w * 16 + kg * 4 + j];

  const int row0 = blockIdx.x * (DEC_NT * 16);

  for (int it = 0; it < DEC_NT; ++it) {
    const int grow = row0 + it * 16 + rowf;      // flat (b,t) row
    const float* zrow = zs + (size_t)grow * DZc;

    // ---- layer 1: h = W1 @ z^T + b1 ----
    f32x4 acc1[2], acc2[2];
    #pragma unroll
    for (int tm = 0; tm < 2; ++tm)
      #pragma unroll
      for (int j = 0; j < 4; ++j) {
        acc1[tm][j] = b1r[tm][j];
        acc2[tm][j] = 0.f;
      }
    #pragma unroll
    for (int kt = 0; kt < 4; ++kt) {
      const int k0 = kt * 32 + kg * 8;
      short8 zhi, zlo;
      pack_hilo8(*(const f32x4*)&zrow[k0], *(const f32x4*)&zrow[k0 + 4],
                 zhi, zlo);
      acc1[0] = __builtin_amdgcn_mfma_f32_16x16x32_bf16(W1hi[0][kt], zhi, acc1[0], 0, 0, 0);
      acc1[1] = __builtin_amdgcn_mfma_f32_16x16x32_bf16(W1hi[1][kt], zhi, acc1[1], 0, 0, 0);
      acc2[0] = __builtin_amdgcn_mfma_f32_16x16x32_bf16(W1hi[0][kt], zlo, acc2[0], 0, 0, 0);
      acc2[0] = __builtin_amdgcn_mfma_f32_16x16x32_bf16(W1lo[0][kt], zhi, acc2[0], 0, 0, 0);
      acc2[1] = __builtin_amdgcn_mfma_f32_16x16x32_bf16(W1hi[1][kt], zlo, acc2[1], 0, 0, 0);
      acc2[1] = __builtin_amdgcn_mfma_f32_16x16x32_bf16(W1lo[1][kt], zhi, acc2[1], 0, 0, 0);
    }

    // ---- tanh + pack h into LDS (C/D layout -> pbuf) ----
    #pragma unroll
    for (int tm = 0; tm < 2; ++tm) {
      u32x4 pk;
      #pragma unroll
      for (int j = 0; j < 4; ++j) {
        const float hv = ftanh(acc1[tm][j] + acc2[tm][j]);
        const unsigned fb = __float_as_uint(hv);
        const float lof = hv - __uint_as_float(fb & 0xFFFF0000u);
        pk[j] = perm_b32(__float_as_uint(lof), fb, 0x07060302u);
      }
      const int comp0 = (2 * w + tm) * 16 + kg * 4;
      *(u32x4*)&pbuf[it & 1][rowf][comp0 ^ swz] = pk;
    }
    SCAN_BAR();

    // ---- layer 2: x = W2 @ h^T + b2 ----
    f32x4 a1, a2;
    #pragma unroll
    for (int j = 0; j < 4; ++j) { a1[j] = b2r[j]; a2[j] = 0.f; }
    #pragma unroll
    for (int kt = 0; kt < 4; ++kt) {
      const int cbase = (kt * 32 + kg * 8) ^ swz;
      const u32x4 p0 = *(const u32x4*)&pbuf[it & 1][rowf][cbase];
      const u32x4 p1 = *(const u32x4*)&pbuf[it & 1][rowf][cbase + 4];
      u32x4 hi4, lo4;
      hi4[0] = perm_b32(p0[1], p0[0], 0x05040100u);
      hi4[1] = perm_b32(p0[3], p0[2], 0x05040100u);
      hi4[2] = perm_b32(p1[1], p1[0], 0x05040100u);
      hi4[3] = perm_b32(p1[3], p1[2], 0x05040100u);
      lo4[0] = perm_b32(p0[1], p0[0], 0x07060302u);
      lo4[1] = perm_b32(p0[3], p0[2], 0x07060302u);
      lo4[2] = perm_b32(p1[1], p1[0], 0x07060302u);
      lo4[3] = perm_b32(p1[3], p1[2], 0x07060302u);
      const short8 Bhi = __builtin_bit_cast(short8, hi4);
      const short8 Blo = __builtin_bit_cast(short8, lo4);
      a1 = __builtin_amdgcn_mfma_f32_16x16x32_bf16(W2hi[kt], Bhi, a1, 0, 0, 0);
      a2 = __builtin_amdgcn_mfma_f32_16x16x32_bf16(W2hi[kt], Blo, a2, 0, 0, 0);
      a2 = __builtin_amdgcn_mfma_f32_16x16x32_bf16(W2lo[kt], Bhi, a2, 0, 0, 0);
    }

    // ---- tanh + store ----
    f32x4 ov;
    #pragma unroll
    for (int j = 0; j < 4; ++j) ov[j] = ftanh(a1[j] + a2[j]);
    *(f32x4*)&out[(size_t)grow * DXc + w * 16 + kg * 4] = ov;
  }
}

extern "C" void kernel_launch(void* const* d_in, const int* in_sizes, int n_in,
                              void* d_out, int out_size, void* d_ws, size_t ws_size,
                              hipStream_t stream) {
  const float* x      = (const float*)d_in[0];
  const float* z0     = (const float*)d_in[1];
  const float* AW     = (const float*)d_in[2];
  const float* hvec   = (const float*)d_in[3];
  const float* alphas = (const float*)d_in[4];
  const float* thetas = (const float*)d_in[5];
  const float* ew1    = (const float*)d_in[6];
  const float* eb1    = (const float*)d_in[7];
  const float* ew2    = (const float*)d_in[8];
  const float* eb2    = (const float*)d_in[9];
  const float* dw1    = (const float*)d_in[10];
  const float* db1    = (const float*)d_in[11];
  const float* dw2    = (const float*)d_in[12];
  const float* db2    = (const float*)d_in[13];

  float* xp = (float*)d_out;                       // (B,T,DX)
  float* zs = xp + (size_t)BB * TT * DXc;          // (B,T,DZ)

  // 1) encoder at the 40 forcing timesteps -> stash into zs slots
  hipLaunchKernelGGL((mlp_kernel<DXc, DZc, DZc, 32, true, false>),
                     dim3(NF * BB / 32), dim3(256), 0, stream,
                     x, ew1, eb1, ew2, eb2, zs);

  // 2) recurrence scan: MFMA, 16-row groups x 41 segments
  hipLaunchKernelGGL(scan_mfma_kernel, dim3((BB / GRP) * NSEG), dim3(256), 0, stream,
                     AW, z0, hvec, alphas, thetas, zs);

  // 3) decoder: MFMA, weights-stationary
  hipLaunchKernelGGL(dec_mfma_kernel, dim3(BB * TT / (DEC_NT * 16)), dim3(256), 0, stream,
                     zs, dw1, db1, dw2, db2, xp);
}